// Round 4
// baseline (258.218 us; speedup 1.0000x reference)
//
#include <hip/hip_runtime.h>

// out[r, i] = sum_{k=0..4} W[i,k] * x[r, i+k-2] + b[i], zero-padded at edges.
// B=8192 rows, C=4096 channels, K=5, fp32.
//
// R1: W loads (80 B lane stride) -> L1/TA line-request bound, 136 us.
// R2: W/bias hoisted to registers, 16 rows/thread -> 90 us. Counters showed
//     NO pipe saturated (HBM 28%, VALU 6%, occ 55%) -> latency-bound, ~6
//     outstanding loads/wave can't cover ~700 cy miss latency.
// R3: batch 4 rows of loads (12 float4 in flight) before computing;
//     8 rows/thread -> 4096 blocks; nontemporal stores so `out` doesn't
//     evict x from L3. (R3 failed compile: nontemporal builtin needs a
//     native vector type, not HIP_vector_type -> use ext_vector_type alias.)

#define B_ROWS 8192
#define C_CH   4096
#define KWIN   5
#define ROWS_PER_BLOCK 8
#define RBATCH 4

typedef float nfloat4 __attribute__((ext_vector_type(4)));

__global__ __launch_bounds__(256) void grouped_linear_kernel(
    const float* __restrict__ x, const float* __restrict__ W,
    const float* __restrict__ bias, float* __restrict__ out)
{
    // chunk = which group of 4 channels this thread owns (0..1023)
    const int chunk = (blockIdx.x << 8) + threadIdx.x;   // gridDim.x == 4
    const int c     = chunk << 2;                        // base channel
    const int r0    = blockIdx.y * ROWS_PER_BLOCK;

    // --- loop-invariant: W rows c..c+3 (20 contiguous floats) + bias ---
    const float4* W4 = (const float4*)(W + (size_t)c * KWIN);
    const float4 w0 = W4[0];  // W[c][0..3]
    const float4 w1 = W4[1];  // W[c][4], W[c+1][0..2]
    const float4 w2 = W4[2];  // W[c+1][3..4], W[c+2][0..1]
    const float4 w3 = W4[3];  // W[c+2][2..4], W[c+3][0]
    const float4 w4 = W4[4];  // W[c+3][1..4]
    const float4 bv = ((const float4*)bias)[chunk];

    const bool has_m = (c > 0);
    const bool has_p = (c + 4 < C_CH);
    const float4 zero = make_float4(0.f, 0.f, 0.f, 0.f);

    const float4* xrow = (const float4*)(x   + (size_t)r0 * C_CH);
    nfloat4*      orow = (nfloat4*)     (out + (size_t)r0 * C_CH);
    const int row_stride = C_CH / 4;

    for (int rb = 0; rb < ROWS_PER_BLOCK; rb += RBATCH) {
        float4 xm[RBATCH], xc[RBATCH], xp[RBATCH];

        // ---- load phase: 12 independent float4 loads in flight ----
        #pragma unroll
        for (int i = 0; i < RBATCH; ++i) {
            const float4* xr = xrow + (size_t)i * row_stride;
            xm[i] = has_m ? xr[chunk - 1] : zero;
            xc[i] = xr[chunk];
            xp[i] = has_p ? xr[chunk + 1] : zero;
        }

        // ---- compute + store phase ----
        #pragma unroll
        for (int i = 0; i < RBATCH; ++i) {
            const float win0 = xm[i].z, win1 = xm[i].w;
            const float win2 = xc[i].x, win3 = xc[i].y, win4 = xc[i].z, win5 = xc[i].w;
            const float win6 = xp[i].x, win7 = xp[i].y;

            nfloat4 o;
            o.x = fmaf(w0.x, win0, fmaf(w0.y, win1, fmaf(w0.z, win2, fmaf(w0.w, win3, fmaf(w1.x, win4, bv.x)))));
            o.y = fmaf(w1.y, win1, fmaf(w1.z, win2, fmaf(w1.w, win3, fmaf(w2.x, win4, fmaf(w2.y, win5, bv.y)))));
            o.z = fmaf(w2.z, win2, fmaf(w2.w, win3, fmaf(w3.x, win4, fmaf(w3.y, win5, fmaf(w3.z, win6, bv.z)))));
            o.w = fmaf(w3.w, win3, fmaf(w4.x, win4, fmaf(w4.y, win5, fmaf(w4.z, win6, fmaf(w4.w, win7, bv.w)))));

            __builtin_nontemporal_store(o, orow + (size_t)i * row_stride + chunk);
        }

        xrow += (size_t)RBATCH * row_stride;
        orow += (size_t)RBATCH * row_stride;
    }
}

extern "C" void kernel_launch(void* const* d_in, const int* in_sizes, int n_in,
                              void* d_out, int out_size, void* d_ws, size_t ws_size,
                              hipStream_t stream) {
    const float* x    = (const float*)d_in[0];
    const float* W    = (const float*)d_in[1];
    const float* bias = (const float*)d_in[2];
    float* out = (float*)d_out;

    dim3 grid(C_CH / 4 / 256, B_ROWS / ROWS_PER_BLOCK);  // (4, 1024) = 4096 blocks
    dim3 block(256);
    grouped_linear_kernel<<<grid, block, 0, stream>>>(x, W, bias, out);
}